// Round 10
// baseline (456.847 us; speedup 1.0000x reference)
//
#include <hip/hip_runtime.h>

// QINCoStep — bs=2048, d=128, K=256, h=256, fp32 in/out.
// Round 10: R9 + k_final3 (exact pass batched 8 b's / wg, 16-row batches)
// to amortize the f32 weight stream: 1 GB -> ~256 MB of L2 traffic.
//
// ws layout (floats):
//   0 WzT 16384 | 16384 WxT 16384 | 32768 W1T0 32768 | 65536 W2T0 32768
//   98304 W1T1 32768 | 131072 W2T1 32768 | 163840 z0 32768 | 196608 u 262144
//   458752 z0bf (32768 us = 16384 fl)   -> ends 475136
//   475136 ubf  (262144 us = 131072 fl) -> ends 606208
//   606208 U1bf (524288 us = 262144 fl) -> ends 868352
//   868352 H1bf (65536 us = 32768 fl)   -> ends 901120
//   901120 F (12288 uint4 = 49152 fl)   -> ends 950272
//   950272 cand (32768 int)             -> ends 983040
//   983040 cnt (4096 int)               -> ends 987136

typedef short bf8_t __attribute__((ext_vector_type(8)));
typedef float f32x16 __attribute__((ext_vector_type(16)));

__device__ inline unsigned short f2bh(float x) {   // RNE f32->bf16 (prep only)
    unsigned u = __float_as_uint(x);
    u += 0x7fffu + ((u >> 16) & 1u);
    return (unsigned short)(u >> 16);
}
__device__ inline float bh2f(unsigned short h) {
    return __uint_as_float(((unsigned)h) << 16);
}
__device__ inline f32x16 mfma_bf(uint4 a, uint4 b, f32x16 c) {
    bf8_t av = __builtin_bit_cast(bf8_t, a);
    bf8_t bv = __builtin_bit_cast(bf8_t, b);
    return __builtin_amdgcn_mfma_f32_32x32x16_bf16(av, bv, c, 0, 0, 0);
}
// truncation pack: hi16(x) low half, hi16(y) high half — 1 v_perm_b32
__device__ inline unsigned packhi(float x, float y) {
    return __builtin_amdgcn_perm(__float_as_uint(y), __float_as_uint(x), 0x07060302u);
}
// (bf16pair hv) + (bf16pair uv) -> relu -> trunc bf16pair
__device__ inline unsigned addrelu2t(unsigned hv, unsigned uv) {
    float a0 = __uint_as_float(hv << 16) + __uint_as_float(uv << 16);
    float a1 = __uint_as_float(hv & 0xFFFF0000u) + __uint_as_float(uv & 0xFFFF0000u);
    return packhi(fmaxf(a0, 0.f), fmaxf(a1, 0.f));
}

#define DELTA 6.5f

// ---------------- prep1: transposes + frag pack ----------------
__global__ __launch_bounds__(256) void k_prep1(
    const float* __restrict__ Wc,
    const float* __restrict__ W1a, const float* __restrict__ W2a,
    const float* __restrict__ W1b, const float* __restrict__ W2b,
    float* __restrict__ WzT, float* __restrict__ WxT,
    float* __restrict__ W1Ta, float* __restrict__ W2Ta,
    float* __restrict__ W1Tb, float* __restrict__ W2Tb,
    uint4* __restrict__ F)
{
    int g = blockIdx.x * 256 + threadIdx.x;
    if (g < 16384) {
        int j = g >> 7, d = g & 127;
        WzT[g] = Wc[d * 256 + j];
    } else if (g < 32768) {
        int e = g - 16384; int j = e >> 7, d = e & 127;
        WxT[e] = Wc[d * 256 + 128 + j];
    } else if (g < 65536) {
        int e = g - 32768; int d = e >> 8, h = e & 255;
        W1Ta[e] = W1a[h * 128 + d];
    } else if (g < 98304) {
        int e = g - 65536; int h = e >> 7, i = e & 127;
        W2Ta[e] = W2a[i * 256 + h];
    } else if (g < 131072) {
        int e = g - 98304; int d = e >> 8, h = e & 255;
        W1Tb[e] = W1b[h * 128 + d];
    } else if (g < 163840) {
        int e = g - 131072; int h = e >> 7, i = e & 127;
        W2Tb[e] = W2b[i * 256 + h];
    } else if (g < 176128) {   // 12288 frag-lane slots (RNE)
        int idx = g - 163840;
        int mat = idx >> 12, fp = idx & 4095;
        int tile = fp >> 6, lane = fp & 63;
        const float* src;
        if (mat == 1) {            // W1_1: [256][128], 8mt x 8kt
            int mt = tile >> 3, kt = tile & 7;
            src = W1b + (32 * mt + (lane & 31)) * 128 + 16 * kt + 8 * (lane >> 5);
        } else {                   // W2-type: [128][256], 4mt x 16kt
            const float* W = (mat == 0) ? W2a : W2b;
            int mt = tile >> 4, kt = tile & 15;
            src = W + (32 * mt + (lane & 31)) * 256 + 16 * kt + 8 * (lane >> 5);
        }
        unsigned short hs[8];
#pragma unroll
        for (int j = 0; j < 8; ++j) hs[j] = f2bh(src[j]);
        uint4 hv;
        hv.x = (unsigned)hs[0] | ((unsigned)hs[1] << 16);
        hv.y = (unsigned)hs[2] | ((unsigned)hs[3] << 16);
        hv.z = (unsigned)hs[4] | ((unsigned)hs[5] << 16);
        hv.w = (unsigned)hs[6] | ((unsigned)hs[7] << 16);
        F[idx] = hv;
    }
}

// ---------------- prep2: k-role (z0, z0bf, H1bf) + b-role (u, ubf, U1bf) ----------------
__global__ __launch_bounds__(256) void k_prep2(
    const float* __restrict__ cb, const float* __restrict__ bc,
    const float* __restrict__ xhat,
    const float* __restrict__ WzT, const float* __restrict__ WxT,
    const float* __restrict__ W1T0,
    float* __restrict__ z0, unsigned short* __restrict__ z0bf,
    unsigned short* __restrict__ H1bf,
    float* __restrict__ u, unsigned short* __restrict__ ubf,
    unsigned short* __restrict__ U1bf)
{
    __shared__ float src[4][128];
    __shared__ float res[4][128];
    const int t = threadIdx.x;
    const bool krole = blockIdx.x < 64;
    const int r0 = (krole ? blockIdx.x : (blockIdx.x - 64)) * 4;
    const float* in = krole ? cb : xhat;
    const float* WT = krole ? WzT : WxT;
#pragma unroll
    for (int e = t; e < 512; e += 256)
        src[e >> 7][e & 127] = in[(r0 + (e >> 7)) * 128 + (e & 127)];
    __syncthreads();
    {
        const int d = t & 127, r = t >> 7;   // rows r, r+2
        float a0 = krole ? (bc[d] + src[r][d]) : 0.f;
        float a1 = krole ? (bc[d] + src[r + 2][d]) : 0.f;
        for (int j = 0; j < 128; ++j) {
            const float w = WT[j * 128 + d];
            a0 = fmaf(src[r][j], w, a0);
            a1 = fmaf(src[r + 2][j], w, a1);
        }
        float* dst = krole ? z0 : u;
        unsigned short* dstbf = krole ? z0bf : ubf;
        dst[(r0 + r) * 128 + d] = a0;        dstbf[(r0 + r) * 128 + d] = f2bh(a0);
        dst[(r0 + r + 2) * 128 + d] = a1;    dstbf[(r0 + r + 2) * 128 + d] = f2bh(a1);
        res[r][d] = a0; res[r + 2][d] = a1;
    }
    __syncthreads();
    {   // t = h: W1_0 . res  (coalesced W1T0 reads)
        float a[4] = {0.f, 0.f, 0.f, 0.f};
        for (int d = 0; d < 128; ++d) {
            const float w = W1T0[d * 256 + t];
#pragma unroll
            for (int r = 0; r < 4; ++r) a[r] = fmaf(res[r][d], w, a[r]);
        }
        if (krole) {   // frag-ordered bf16
            const int kt = t >> 4, half = (t >> 3) & 1, j = t & 7;
#pragma unroll
            for (int r = 0; r < 4; ++r) {
                int k = r0 + r; int kg = k >> 5, col = k & 31;
                H1bf[(((kg * 16 + kt) * 64) + half * 32 + col) * 8 + j] = f2bh(a[r]);
            }
        } else {
#pragma unroll
            for (int r = 0; r < 4; ++r)
                U1bf[(r0 + r) * 256 + t] = f2bh(a[r]);
        }
    }
}

// ---------------- main: approx dist + fused per-half select (unchanged from R9) ----------------
__global__ __launch_bounds__(512, 6) void k_dist_approx(
    const unsigned short* __restrict__ z0bf, const unsigned short* __restrict__ ubf,
    const float* __restrict__ xhat, const float* __restrict__ x,
    const uint4* __restrict__ H1u4, const unsigned short* __restrict__ U1bf,
    const uint4* __restrict__ W2f0, const uint4* __restrict__ W1f1,
    const uint4* __restrict__ W2f1,
    int* __restrict__ cand, int* __restrict__ cnt)
{
    __shared__ uint4 Zf[2048];   // 32 KB
    __shared__ uint4 Hf[1024];   // 16 KB; tail reused for red/sdist/sk

    const int t = threadIdx.x;
    const int lane = t & 63, wave = t >> 6;
    const int wm = wave & 3, wn = wave >> 2;
    const int l31 = lane & 31, l5 = lane >> 5;
    const int b = blockIdx.x >> 1, q = blockIdx.x & 1;
    const int k0 = q << 7;

    f32x16 zs[2];
    {
        const unsigned short* ur = ubf + b * 128;
#pragma unroll
        for (int g = 0; g < 2; ++g) {
            const int col = ((wn << 1) + g) * 32 + l31;
            const unsigned short* zr = z0bf + (k0 + col) * 128;
#pragma unroll
            for (int rg = 0; rg < 4; ++rg) {
                const int d0 = 32 * wm + 8 * rg + 4 * l5;
                ushort4 a = *(const ushort4*)(zr + d0);
                ushort4 c = *(const ushort4*)(ur + d0);
                zs[g][4*rg+0] = bh2f(a.x) + bh2f(c.x);
                zs[g][4*rg+1] = bh2f(a.y) + bh2f(c.y);
                zs[g][4*rg+2] = bh2f(a.z) + bh2f(c.z);
                zs[g][4*rg+3] = bh2f(a.w) + bh2f(c.w);
            }
        }
    }

#pragma unroll 1
    for (int r = 0; r < 4; ++r) {
        {
            const int kt = 4 * r + wm;
            const uint4 uv = *(const uint4*)(U1bf + b * 256 + kt * 16 + 8 * l5);
#pragma unroll
            for (int gi = 0; gi < 2; ++gi) {
                const int cg = (wn << 1) + gi;
                const int kg = (q << 2) + cg;
                uint4 hv = H1u4[(kg * 16 + kt) * 64 + lane];
                uint4 o;
                o.x = addrelu2t(hv.x, uv.x);
                o.y = addrelu2t(hv.y, uv.y);
                o.z = addrelu2t(hv.z, uv.z);
                o.w = addrelu2t(hv.w, uv.w);
                Hf[((cg << 2) + wm) * 64 + lane] = o;
            }
        }
        __syncthreads();
#pragma unroll
        for (int ktl = 0; ktl < 4; ++ktl) {
            uint4 ah = W2f0[((wm << 4) + 4 * r + ktl) * 64 + lane];
#pragma unroll
            for (int g = 0; g < 2; ++g) {
                uint4 bv = Hf[((((wn << 1) + g) << 2) + ktl) * 64 + lane];
                zs[g] = mfma_bf(ah, bv, zs[g]);
            }
        }
        __syncthreads();
    }

#pragma unroll
    for (int g = 0; g < 2; ++g) {
        const int cg = (wn << 1) + g;
#pragma unroll
        for (int rg = 0; rg < 4; ++rg) {
            uint2 hv;
            hv.x = packhi(zs[g][4*rg+0], zs[g][4*rg+1]);
            hv.y = packhi(zs[g][4*rg+2], zs[g][4*rg+3]);
            uint2* zb2 = (uint2*)&Zf[((cg << 3) + 2 * wm + (rg >> 1)) * 64];
            zb2[(((rg & 1) << 5) + l31) * 2 + l5] = hv;
        }
    }
    __syncthreads();

    const int tile = wave & 1, cg1 = wave >> 1;
#pragma unroll 1
    for (int c = 0; c < 4; ++c) {
        f32x16 acc;
#pragma unroll
        for (int rr = 0; rr < 16; ++rr) acc[rr] = 0.f;
        {
            const uint4* pw1 = W1f1 + ((2 * c + tile) << 3) * 64;
#pragma unroll
            for (int kt = 0; kt < 8; ++kt) {
                uint4 bv = Zf[((cg1 << 3) + kt) * 64 + lane];
                uint4 ah = pw1[kt * 64 + lane];
                acc = mfma_bf(ah, bv, acc);
            }
        }
        __syncthreads();
#pragma unroll
        for (int rg = 0; rg < 4; ++rg) {
            float v0 = fmaxf(acc[4*rg+0], 0.f), v1 = fmaxf(acc[4*rg+1], 0.f);
            float v2 = fmaxf(acc[4*rg+2], 0.f), v3 = fmaxf(acc[4*rg+3], 0.f);
            uint2 hv; hv.x = packhi(v0, v1); hv.y = packhi(v2, v3);
            uint2* hb2 = (uint2*)&Hf[((cg1 << 2) + (tile << 1) + (rg >> 1)) * 64];
            hb2[(((rg & 1) << 5) + l31) * 2 + l5] = hv;
        }
        __syncthreads();
#pragma unroll
        for (int ktl = 0; ktl < 4; ++ktl) {
            uint4 ah = W2f1[((wm << 4) + 4 * c + ktl) * 64 + lane];
#pragma unroll
            for (int g = 0; g < 2; ++g) {
                uint4 bv = Hf[((((wn << 1) + g) << 2) + ktl) * 64 + lane];
                zs[g] = mfma_bf(ah, bv, zs[g]);
            }
        }
    }

    float* red   = (float*)Hf;          // [4][128]
    float* sdist = (float*)Hf + 512;    // [128]
    int*   sk    = (int*)((float*)Hf + 640);   // [8]
    __syncthreads();
#pragma unroll
    for (int g = 0; g < 2; ++g) {
        float s = 0.f;
        const int col = ((wn << 1) + g) * 32 + l31;
#pragma unroll
        for (int rg = 0; rg < 4; ++rg) {
            const int d0 = 32 * wm + 8 * rg + 4 * l5;
            float4 xh = *(const float4*)(xhat + b * 128 + d0);
            float4 xx = *(const float4*)(x + b * 128 + d0);
            float v;
            v = zs[g][4*rg+0] + xh.x - xx.x; s = fmaf(v, v, s);
            v = zs[g][4*rg+1] + xh.y - xx.y; s = fmaf(v, v, s);
            v = zs[g][4*rg+2] + xh.z - xx.z; s = fmaf(v, v, s);
            v = zs[g][4*rg+3] + xh.w - xx.w; s = fmaf(v, v, s);
        }
        s += __shfl_xor(s, 32, 64);
        if (l5 == 0) red[wm * 128 + col] = s;
    }
    __syncthreads();
    if (t < 128)
        sdist[t] = red[t] + red[128 + t] + red[256 + t] + red[384 + t];
    __syncthreads();
    if (wave == 0) {
        int base = 0;
        float v0 = sdist[lane], v1 = sdist[lane + 64];
        float m = fminf(v0, v1);
#pragma unroll
        for (int off = 32; off > 0; off >>= 1) m = fminf(m, __shfl_xor(m, off, 64));
        const float thr = m + DELTA;
        const unsigned long long below = (1ull << lane) - 1;
        float vv[2] = {v0, v1};
#pragma unroll
        for (int j = 0; j < 2; ++j) {
            bool p = vv[j] <= thr;
            unsigned long long mask = __ballot(p);
            int pos = base + __popcll(mask & below);
            if (p && pos < 8) sk[pos] = k0 + 64 * j + lane;   // k-ascending order
            base += __popcll(mask);
        }
        if (lane == 0) {
            int c = base > 8 ? 8 : base;
            cnt[b * 2 + q] = c;
            for (int s2 = 0; s2 < c; ++s2)
                cand[(b * 2 + q) * 8 + s2] = sk[s2];
        }
    }
}

// ---------------- final3: 8 b's per wg, 16-row batches, weight-stream amortized ----------------
__global__ __launch_bounds__(256) void k_final3(
    const float* __restrict__ z0, const float* __restrict__ u,
    const float* __restrict__ xhat, const float* __restrict__ x,
    const int* __restrict__ cand, const int* __restrict__ cnt,
    const float* __restrict__ W1Ta, const float* __restrict__ W2Ta,
    const float* __restrict__ W1Tb, const float* __restrict__ W2Tb,
    float* __restrict__ out0, float* __restrict__ outd)
{
    __shared__ float z16[16][128];    // 8 KB
    __shared__ float h16[16][256];    // 16 KB (tail reused as part[16][16])
    __shared__ float zwin[8][128];    // 4 KB
    __shared__ int rowb[128], rowk[128];
    __shared__ int off[8];
    __shared__ int rtot;
    __shared__ float dd[16];
    __shared__ float dbest[8];
    __shared__ int kbest[8];
    __shared__ int copyrow[8];
    const int t = threadIdx.x;
    const int b0 = blockIdx.x * 8;

    // build row list (k-ascending per b: half0 slots then half1 slots)
    if (t < 8) {
        int c0 = cnt[2 * (b0 + t)], c1 = cnt[2 * (b0 + t) + 1];
        int tb = c0 + c1;
        // exclusive scan over 8 counts via shuffle-free LDS (small)
        off[t] = tb;
        dbest[t] = 3.4e38f;
        kbest[t] = 0;
    }
    __syncthreads();
    if (t == 0) {
        int a = 0;
        for (int i = 0; i < 8; ++i) { int v = off[i]; off[i] = a; a += v; }
        rtot = a;
    }
    __syncthreads();
    if (t < 8) {
        int c0 = cnt[2 * (b0 + t)], c1 = cnt[2 * (b0 + t) + 1];
        int o = off[t];
        for (int s = 0; s < c0; ++s) { rowb[o] = t; rowk[o] = cand[(2 * (b0 + t)) * 8 + s]; ++o; }
        for (int s = 0; s < c1; ++s) { rowb[o] = t; rowk[o] = cand[(2 * (b0 + t) + 1) * 8 + s]; ++o; }
    }
    __syncthreads();
    const int R = rtot;
    const int nb = (R + 15) >> 4;

#pragma unroll 1
    for (int batch = 0; batch < nb; ++batch) {
        const int rb0 = batch * 16;
        const int nr = (R - rb0) < 16 ? (R - rb0) : 16;
        // z init (pad rows replicate row rb0)
#pragma unroll
        for (int n = 0; n < 8; ++n) {
            int e = n * 256 + t; int r = e >> 7, d = e & 127;
            int rg = rb0 + (r < nr ? r : 0);
            z16[r][d] = z0[rowk[rg] * 128 + d] + u[(b0 + rowb[rg]) * 128 + d];
        }
        __syncthreads();
        const float* W1T = W1Ta; const float* W2T = W2Ta;
#pragma unroll 1
        for (int blk = 0; blk < 2; ++blk) {
            float a1[16];
#pragma unroll
            for (int r = 0; r < 16; ++r) a1[r] = 0.f;
            for (int d = 0; d < 128; ++d) {
                const float w = W1T[d * 256 + t];
#pragma unroll
                for (int r = 0; r < 16; ++r) a1[r] = fmaf(z16[r][d], w, a1[r]);
            }
#pragma unroll
            for (int r = 0; r < 16; ++r) h16[r][t] = fmaxf(a1[r], 0.f);
            __syncthreads();
            const int ig = t & 127, rq = (t >> 7) * 8;
            float a2[8];
#pragma unroll
            for (int j = 0; j < 8; ++j) a2[j] = 0.f;
            for (int h = 0; h < 256; ++h) {
                const float w = W2T[h * 128 + ig];
#pragma unroll
                for (int j = 0; j < 8; ++j) a2[j] = fmaf(h16[rq + j][h], w, a2[j]);
            }
            __syncthreads();
#pragma unroll
            for (int j = 0; j < 8; ++j) z16[rq + j][ig] += a2[j];
            __syncthreads();
            W1T = W1Tb; W2T = W2Tb;
        }
        {   // exact dist per row (part overlays h16)
            float* part = (float*)h16;
            const int r = t >> 4, c = t & 15;
            const int bl = rowb[rb0 + (r < nr ? r : 0)];
            float s = 0.f;
#pragma unroll
            for (int i = 0; i < 8; ++i) {
                int d = c * 8 + i;
                float v = z16[r][d] + xhat[(b0 + bl) * 128 + d] - x[(b0 + bl) * 128 + d];
                s = fmaf(v, v, s);
            }
            part[r * 16 + c] = s;
            __syncthreads();
            if (t < 16) {
                float ssum = 0.f;
#pragma unroll
                for (int c2 = 0; c2 < 16; ++c2) ssum += part[t * 16 + c2];
                dd[t] = ssum;
            }
        }
        if (t < 8) copyrow[t] = -1;
        __syncthreads();
        // per-b running min (rows are k-ascending; strict < keeps lowest k)
        if (t < 8) {
            for (int r = 0; r < nr; ++r) {
                if (rowb[rb0 + r] == t && dd[r] < dbest[t]) {
                    dbest[t] = dd[r];
                    kbest[t] = rowk[rb0 + r];
                    copyrow[t] = r;
                }
            }
        }
        __syncthreads();
        if (t < 128) {
#pragma unroll 1
            for (int bl = 0; bl < 8; ++bl) {
                int cr = copyrow[bl];
                if (cr >= 0) zwin[bl][t] = z16[cr][t];
            }
        }
        __syncthreads();
    }

    if (t < 8) out0[b0 + t] = (float)kbest[t];
#pragma unroll
    for (int n = 0; n < 4; ++n) {
        int e = n * 256 + t; int bl = e >> 7, d = e & 127;
        outd[(b0 + bl) * 128 + d] = zwin[bl][d];
    }
}

extern "C" void kernel_launch(void* const* d_in, const int* in_sizes, int n_in,
                              void* d_out, int out_size, void* d_ws, size_t ws_size,
                              hipStream_t stream) {
    const float* xhat = (const float*)d_in[0];
    const float* x    = (const float*)d_in[1];
    const float* cb   = (const float*)d_in[2];
    const float* Wc   = (const float*)d_in[3];
    const float* bc   = (const float*)d_in[4];
    const float* W1_0 = (const float*)d_in[5];
    const float* W2_0 = (const float*)d_in[6];
    const float* W1_1 = (const float*)d_in[7];
    const float* W2_1 = (const float*)d_in[8];
    float* out = (float*)d_out;
    float* ws  = (float*)d_ws;

    float* WzT   = ws + 0;
    float* WxT   = ws + 16384;
    float* W1T0  = ws + 32768;
    float* W2T0  = ws + 65536;
    float* W1T1  = ws + 98304;
    float* W2T1  = ws + 131072;
    float* z0    = ws + 163840;
    float* u     = ws + 196608;
    unsigned short* z0bf = (unsigned short*)(ws + 458752);
    unsigned short* ubf  = (unsigned short*)(ws + 475136);
    unsigned short* U1bf = (unsigned short*)(ws + 606208);
    unsigned short* H1bf = (unsigned short*)(ws + 868352);
    uint4* F     = (uint4*)(ws + 901120);
    const uint4* W2f0 = F;
    const uint4* W1f1 = F + 4096;
    const uint4* W2f1 = F + 8192;
    int* cand = (int*)(ws + 950272);
    int* cnt  = (int*)(ws + 983040);

    k_prep1<<<688, 256, 0, stream>>>(Wc, W1_0, W2_0, W1_1, W2_1,
                                     WzT, WxT, W1T0, W2T0, W1T1, W2T1, F);
    k_prep2<<<576, 256, 0, stream>>>(cb, bc, xhat, WzT, WxT, W1T0,
                                     z0, z0bf, H1bf, u, ubf, U1bf);
    k_dist_approx<<<4096, 512, 0, stream>>>(z0bf, ubf, xhat, x, (const uint4*)H1bf,
                                            U1bf, W2f0, W1f1, W2f1, cand, cnt);
    k_final3<<<256, 256, 0, stream>>>(z0, u, xhat, x, cand, cnt,
                                      W1T0, W2T0, W1T1, W2T1, out, out + 2048);
}

// Round 11
// 331.794 us; speedup vs baseline: 1.3769x; 1.3769x over previous
//
#include <hip/hip_runtime.h>

// QINCoStep — bs=2048, d=128, K=256, h=256, fp32 in/out.
// Round 11: R10 with k_final4 — same 8-b weight-stream amortization but
// 1024 threads / 16 waves per wg (4 waves/SIMD restores latency hiding;
// R10's k_final3 at 4 waves/wg ran 1 wave/SIMD and stalled on L2 latency).
//
// ws layout (floats):
//   0 WzT 16384 | 16384 WxT 16384 | 32768 W1T0 32768 | 65536 W2T0 32768
//   98304 W1T1 32768 | 131072 W2T1 32768 | 163840 z0 32768 | 196608 u 262144
//   458752 z0bf | 475136 ubf | 606208 U1bf | 868352 H1bf
//   901120 F (12288 uint4) | 950272 cand (32768 int) | 983040 cnt (4096 int)

typedef short bf8_t __attribute__((ext_vector_type(8)));
typedef float f32x16 __attribute__((ext_vector_type(16)));

__device__ inline unsigned short f2bh(float x) {   // RNE f32->bf16 (prep only)
    unsigned u = __float_as_uint(x);
    u += 0x7fffu + ((u >> 16) & 1u);
    return (unsigned short)(u >> 16);
}
__device__ inline float bh2f(unsigned short h) {
    return __uint_as_float(((unsigned)h) << 16);
}
__device__ inline f32x16 mfma_bf(uint4 a, uint4 b, f32x16 c) {
    bf8_t av = __builtin_bit_cast(bf8_t, a);
    bf8_t bv = __builtin_bit_cast(bf8_t, b);
    return __builtin_amdgcn_mfma_f32_32x32x16_bf16(av, bv, c, 0, 0, 0);
}
__device__ inline unsigned packhi(float x, float y) {
    return __builtin_amdgcn_perm(__float_as_uint(y), __float_as_uint(x), 0x07060302u);
}
__device__ inline unsigned addrelu2t(unsigned hv, unsigned uv) {
    float a0 = __uint_as_float(hv << 16) + __uint_as_float(uv << 16);
    float a1 = __uint_as_float(hv & 0xFFFF0000u) + __uint_as_float(uv & 0xFFFF0000u);
    return packhi(fmaxf(a0, 0.f), fmaxf(a1, 0.f));
}

#define DELTA 6.5f

// ---------------- prep1: transposes + frag pack ----------------
__global__ __launch_bounds__(256) void k_prep1(
    const float* __restrict__ Wc,
    const float* __restrict__ W1a, const float* __restrict__ W2a,
    const float* __restrict__ W1b, const float* __restrict__ W2b,
    float* __restrict__ WzT, float* __restrict__ WxT,
    float* __restrict__ W1Ta, float* __restrict__ W2Ta,
    float* __restrict__ W1Tb, float* __restrict__ W2Tb,
    uint4* __restrict__ F)
{
    int g = blockIdx.x * 256 + threadIdx.x;
    if (g < 16384) {
        int j = g >> 7, d = g & 127;
        WzT[g] = Wc[d * 256 + j];
    } else if (g < 32768) {
        int e = g - 16384; int j = e >> 7, d = e & 127;
        WxT[e] = Wc[d * 256 + 128 + j];
    } else if (g < 65536) {
        int e = g - 32768; int d = e >> 8, h = e & 255;
        W1Ta[e] = W1a[h * 128 + d];
    } else if (g < 98304) {
        int e = g - 65536; int h = e >> 7, i = e & 127;
        W2Ta[e] = W2a[i * 256 + h];
    } else if (g < 131072) {
        int e = g - 98304; int d = e >> 8, h = e & 255;
        W1Tb[e] = W1b[h * 128 + d];
    } else if (g < 163840) {
        int e = g - 131072; int h = e >> 7, i = e & 127;
        W2Tb[e] = W2b[i * 256 + h];
    } else if (g < 176128) {   // 12288 frag-lane slots (RNE)
        int idx = g - 163840;
        int mat = idx >> 12, fp = idx & 4095;
        int tile = fp >> 6, lane = fp & 63;
        const float* src;
        if (mat == 1) {            // W1_1: [256][128], 8mt x 8kt
            int mt = tile >> 3, kt = tile & 7;
            src = W1b + (32 * mt + (lane & 31)) * 128 + 16 * kt + 8 * (lane >> 5);
        } else {                   // W2-type: [128][256], 4mt x 16kt
            const float* W = (mat == 0) ? W2a : W2b;
            int mt = tile >> 4, kt = tile & 15;
            src = W + (32 * mt + (lane & 31)) * 256 + 16 * kt + 8 * (lane >> 5);
        }
        unsigned short hs[8];
#pragma unroll
        for (int j = 0; j < 8; ++j) hs[j] = f2bh(src[j]);
        uint4 hv;
        hv.x = (unsigned)hs[0] | ((unsigned)hs[1] << 16);
        hv.y = (unsigned)hs[2] | ((unsigned)hs[3] << 16);
        hv.z = (unsigned)hs[4] | ((unsigned)hs[5] << 16);
        hv.w = (unsigned)hs[6] | ((unsigned)hs[7] << 16);
        F[idx] = hv;
    }
}

// ---------------- prep2: k-role (z0, z0bf, H1bf) + b-role (u, ubf, U1bf) ----------------
__global__ __launch_bounds__(256) void k_prep2(
    const float* __restrict__ cb, const float* __restrict__ bc,
    const float* __restrict__ xhat,
    const float* __restrict__ WzT, const float* __restrict__ WxT,
    const float* __restrict__ W1T0,
    float* __restrict__ z0, unsigned short* __restrict__ z0bf,
    unsigned short* __restrict__ H1bf,
    float* __restrict__ u, unsigned short* __restrict__ ubf,
    unsigned short* __restrict__ U1bf)
{
    __shared__ float src[4][128];
    __shared__ float res[4][128];
    const int t = threadIdx.x;
    const bool krole = blockIdx.x < 64;
    const int r0 = (krole ? blockIdx.x : (blockIdx.x - 64)) * 4;
    const float* in = krole ? cb : xhat;
    const float* WT = krole ? WzT : WxT;
#pragma unroll
    for (int e = t; e < 512; e += 256)
        src[e >> 7][e & 127] = in[(r0 + (e >> 7)) * 128 + (e & 127)];
    __syncthreads();
    {
        const int d = t & 127, r = t >> 7;   // rows r, r+2
        float a0 = krole ? (bc[d] + src[r][d]) : 0.f;
        float a1 = krole ? (bc[d] + src[r + 2][d]) : 0.f;
        for (int j = 0; j < 128; ++j) {
            const float w = WT[j * 128 + d];
            a0 = fmaf(src[r][j], w, a0);
            a1 = fmaf(src[r + 2][j], w, a1);
        }
        float* dst = krole ? z0 : u;
        unsigned short* dstbf = krole ? z0bf : ubf;
        dst[(r0 + r) * 128 + d] = a0;        dstbf[(r0 + r) * 128 + d] = f2bh(a0);
        dst[(r0 + r + 2) * 128 + d] = a1;    dstbf[(r0 + r + 2) * 128 + d] = f2bh(a1);
        res[r][d] = a0; res[r + 2][d] = a1;
    }
    __syncthreads();
    {   // t = h: W1_0 . res  (coalesced W1T0 reads)
        float a[4] = {0.f, 0.f, 0.f, 0.f};
        for (int d = 0; d < 128; ++d) {
            const float w = W1T0[d * 256 + t];
#pragma unroll
            for (int r = 0; r < 4; ++r) a[r] = fmaf(res[r][d], w, a[r]);
        }
        if (krole) {   // frag-ordered bf16
            const int kt = t >> 4, half = (t >> 3) & 1, j = t & 7;
#pragma unroll
            for (int r = 0; r < 4; ++r) {
                int k = r0 + r; int kg = k >> 5, col = k & 31;
                H1bf[(((kg * 16 + kt) * 64) + half * 32 + col) * 8 + j] = f2bh(a[r]);
            }
        } else {
#pragma unroll
            for (int r = 0; r < 4; ++r)
                U1bf[(r0 + r) * 256 + t] = f2bh(a[r]);
        }
    }
}

// ---------------- main: approx dist + fused per-half select (unchanged) ----------------
__global__ __launch_bounds__(512, 6) void k_dist_approx(
    const unsigned short* __restrict__ z0bf, const unsigned short* __restrict__ ubf,
    const float* __restrict__ xhat, const float* __restrict__ x,
    const uint4* __restrict__ H1u4, const unsigned short* __restrict__ U1bf,
    const uint4* __restrict__ W2f0, const uint4* __restrict__ W1f1,
    const uint4* __restrict__ W2f1,
    int* __restrict__ cand, int* __restrict__ cnt)
{
    __shared__ uint4 Zf[2048];   // 32 KB
    __shared__ uint4 Hf[1024];   // 16 KB; tail reused for red/sdist/sk

    const int t = threadIdx.x;
    const int lane = t & 63, wave = t >> 6;
    const int wm = wave & 3, wn = wave >> 2;
    const int l31 = lane & 31, l5 = lane >> 5;
    const int b = blockIdx.x >> 1, q = blockIdx.x & 1;
    const int k0 = q << 7;

    f32x16 zs[2];
    {
        const unsigned short* ur = ubf + b * 128;
#pragma unroll
        for (int g = 0; g < 2; ++g) {
            const int col = ((wn << 1) + g) * 32 + l31;
            const unsigned short* zr = z0bf + (k0 + col) * 128;
#pragma unroll
            for (int rg = 0; rg < 4; ++rg) {
                const int d0 = 32 * wm + 8 * rg + 4 * l5;
                ushort4 a = *(const ushort4*)(zr + d0);
                ushort4 c = *(const ushort4*)(ur + d0);
                zs[g][4*rg+0] = bh2f(a.x) + bh2f(c.x);
                zs[g][4*rg+1] = bh2f(a.y) + bh2f(c.y);
                zs[g][4*rg+2] = bh2f(a.z) + bh2f(c.z);
                zs[g][4*rg+3] = bh2f(a.w) + bh2f(c.w);
            }
        }
    }

#pragma unroll 1
    for (int r = 0; r < 4; ++r) {
        {
            const int kt = 4 * r + wm;
            const uint4 uv = *(const uint4*)(U1bf + b * 256 + kt * 16 + 8 * l5);
#pragma unroll
            for (int gi = 0; gi < 2; ++gi) {
                const int cg = (wn << 1) + gi;
                const int kg = (q << 2) + cg;
                uint4 hv = H1u4[(kg * 16 + kt) * 64 + lane];
                uint4 o;
                o.x = addrelu2t(hv.x, uv.x);
                o.y = addrelu2t(hv.y, uv.y);
                o.z = addrelu2t(hv.z, uv.z);
                o.w = addrelu2t(hv.w, uv.w);
                Hf[((cg << 2) + wm) * 64 + lane] = o;
            }
        }
        __syncthreads();
#pragma unroll
        for (int ktl = 0; ktl < 4; ++ktl) {
            uint4 ah = W2f0[((wm << 4) + 4 * r + ktl) * 64 + lane];
#pragma unroll
            for (int g = 0; g < 2; ++g) {
                uint4 bv = Hf[((((wn << 1) + g) << 2) + ktl) * 64 + lane];
                zs[g] = mfma_bf(ah, bv, zs[g]);
            }
        }
        __syncthreads();
    }

#pragma unroll
    for (int g = 0; g < 2; ++g) {
        const int cg = (wn << 1) + g;
#pragma unroll
        for (int rg = 0; rg < 4; ++rg) {
            uint2 hv;
            hv.x = packhi(zs[g][4*rg+0], zs[g][4*rg+1]);
            hv.y = packhi(zs[g][4*rg+2], zs[g][4*rg+3]);
            uint2* zb2 = (uint2*)&Zf[((cg << 3) + 2 * wm + (rg >> 1)) * 64];
            zb2[(((rg & 1) << 5) + l31) * 2 + l5] = hv;
        }
    }
    __syncthreads();

    const int tile = wave & 1, cg1 = wave >> 1;
#pragma unroll 1
    for (int c = 0; c < 4; ++c) {
        f32x16 acc;
#pragma unroll
        for (int rr = 0; rr < 16; ++rr) acc[rr] = 0.f;
        {
            const uint4* pw1 = W1f1 + ((2 * c + tile) << 3) * 64;
#pragma unroll
            for (int kt = 0; kt < 8; ++kt) {
                uint4 bv = Zf[((cg1 << 3) + kt) * 64 + lane];
                uint4 ah = pw1[kt * 64 + lane];
                acc = mfma_bf(ah, bv, acc);
            }
        }
        __syncthreads();
#pragma unroll
        for (int rg = 0; rg < 4; ++rg) {
            float v0 = fmaxf(acc[4*rg+0], 0.f), v1 = fmaxf(acc[4*rg+1], 0.f);
            float v2 = fmaxf(acc[4*rg+2], 0.f), v3 = fmaxf(acc[4*rg+3], 0.f);
            uint2 hv; hv.x = packhi(v0, v1); hv.y = packhi(v2, v3);
            uint2* hb2 = (uint2*)&Hf[((cg1 << 2) + (tile << 1) + (rg >> 1)) * 64];
            hb2[(((rg & 1) << 5) + l31) * 2 + l5] = hv;
        }
        __syncthreads();
#pragma unroll
        for (int ktl = 0; ktl < 4; ++ktl) {
            uint4 ah = W2f1[((wm << 4) + 4 * c + ktl) * 64 + lane];
#pragma unroll
            for (int g = 0; g < 2; ++g) {
                uint4 bv = Hf[((((wn << 1) + g) << 2) + ktl) * 64 + lane];
                zs[g] = mfma_bf(ah, bv, zs[g]);
            }
        }
    }

    float* red   = (float*)Hf;          // [4][128]
    float* sdist = (float*)Hf + 512;    // [128]
    int*   sk    = (int*)((float*)Hf + 640);   // [8]
    __syncthreads();
#pragma unroll
    for (int g = 0; g < 2; ++g) {
        float s = 0.f;
        const int col = ((wn << 1) + g) * 32 + l31;
#pragma unroll
        for (int rg = 0; rg < 4; ++rg) {
            const int d0 = 32 * wm + 8 * rg + 4 * l5;
            float4 xh = *(const float4*)(xhat + b * 128 + d0);
            float4 xx = *(const float4*)(x + b * 128 + d0);
            float v;
            v = zs[g][4*rg+0] + xh.x - xx.x; s = fmaf(v, v, s);
            v = zs[g][4*rg+1] + xh.y - xx.y; s = fmaf(v, v, s);
            v = zs[g][4*rg+2] + xh.z - xx.z; s = fmaf(v, v, s);
            v = zs[g][4*rg+3] + xh.w - xx.w; s = fmaf(v, v, s);
        }
        s += __shfl_xor(s, 32, 64);
        if (l5 == 0) red[wm * 128 + col] = s;
    }
    __syncthreads();
    if (t < 128)
        sdist[t] = red[t] + red[128 + t] + red[256 + t] + red[384 + t];
    __syncthreads();
    if (wave == 0) {
        int base = 0;
        float v0 = sdist[lane], v1 = sdist[lane + 64];
        float m = fminf(v0, v1);
#pragma unroll
        for (int off = 32; off > 0; off >>= 1) m = fminf(m, __shfl_xor(m, off, 64));
        const float thr = m + DELTA;
        const unsigned long long below = (1ull << lane) - 1;
        float vv[2] = {v0, v1};
#pragma unroll
        for (int j = 0; j < 2; ++j) {
            bool p = vv[j] <= thr;
            unsigned long long mask = __ballot(p);
            int pos = base + __popcll(mask & below);
            if (p && pos < 8) sk[pos] = k0 + 64 * j + lane;   // k-ascending order
            base += __popcll(mask);
        }
        if (lane == 0) {
            int c = base > 8 ? 8 : base;
            cnt[b * 2 + q] = c;
            for (int s2 = 0; s2 < c; ++s2)
                cand[(b * 2 + q) * 8 + s2] = sk[s2];
        }
    }
}

// ---------------- final4: 8 b's / wg, 1024 thr / 16 waves, 32-row batches ----------------
__global__ __launch_bounds__(1024) void k_final4(
    const float* __restrict__ z0, const float* __restrict__ u,
    const float* __restrict__ xhat, const float* __restrict__ x,
    const int* __restrict__ cand, const int* __restrict__ cnt,
    const float* __restrict__ W1Ta, const float* __restrict__ W2Ta,
    const float* __restrict__ W1Tb, const float* __restrict__ W2Tb,
    float* __restrict__ out0, float* __restrict__ outd)
{
    __shared__ float z32[32][128];    // 16 KB
    __shared__ float h32[32][256];    // 32 KB (overlaid as part[32][32] for dist)
    __shared__ float zwin[8][128];    // 4 KB
    __shared__ int rowb[128], rowk[128];
    __shared__ int off[8];
    __shared__ int rtot;
    __shared__ float dd[32];
    __shared__ float dbest[8];
    __shared__ int kbest[8];
    __shared__ int copyrow[8];
    const int t = threadIdx.x;
    const int b0 = blockIdx.x * 8;

    if (t < 8) {
        off[t] = cnt[2 * (b0 + t)] + cnt[2 * (b0 + t) + 1];
        dbest[t] = 3.4e38f;
        kbest[t] = 0;
    }
    __syncthreads();
    if (t == 0) {
        int a = 0;
        for (int i = 0; i < 8; ++i) { int v = off[i]; off[i] = a; a += v; }
        rtot = a;
    }
    __syncthreads();
    if (t < 8) {   // rows k-ascending per b (half0 ks < half1 ks)
        int c0 = cnt[2 * (b0 + t)], c1 = cnt[2 * (b0 + t) + 1];
        int o = off[t];
        for (int s = 0; s < c0; ++s) { rowb[o] = t; rowk[o] = cand[(2 * (b0 + t)) * 8 + s]; ++o; }
        for (int s = 0; s < c1; ++s) { rowb[o] = t; rowk[o] = cand[(2 * (b0 + t) + 1) * 8 + s]; ++o; }
    }
    __syncthreads();
    const int R = rtot;
    const int nb = (R + 31) >> 5;

#pragma unroll 1
    for (int batch = 0; batch < nb; ++batch) {
        const int rb0 = batch * 32;
        const int nr = (R - rb0) < 32 ? (R - rb0) : 32;
#pragma unroll
        for (int n = 0; n < 4; ++n) {   // z init: 4096 elems / 1024 thr
            int e = n * 1024 + t; int r = e >> 7, d = e & 127;
            int rg = rb0 + (r < nr ? r : 0);
            z32[r][d] = z0[rowk[rg] * 128 + d] + u[(b0 + rowb[rg]) * 128 + d];
        }
        __syncthreads();
        const float* W1T = W1Ta; const float* W2T = W2Ta;
#pragma unroll 1
        for (int blk = 0; blk < 2; ++blk) {
            {   // G1: t = (h 0..255, rq 0..3 of 8 rows)
                const int hh = t & 255, rq = (t >> 8) * 8;
                float a1[8];
#pragma unroll
                for (int j = 0; j < 8; ++j) a1[j] = 0.f;
                for (int d = 0; d < 128; ++d) {
                    const float w = W1T[d * 256 + hh];   // coalesced
#pragma unroll
                    for (int j = 0; j < 8; ++j) a1[j] = fmaf(z32[rq + j][d], w, a1[j]);
                }
#pragma unroll
                for (int j = 0; j < 8; ++j) h32[rq + j][hh] = fmaxf(a1[j], 0.f);
            }
            __syncthreads();
            {   // G2: t = (i 0..127, rq 0..7 of 4 rows)
                const int ii = t & 127, rq = (t >> 7) * 4;
                float a2[4] = {0.f, 0.f, 0.f, 0.f};
                for (int h = 0; h < 256; ++h) {
                    const float w = W2T[h * 128 + ii];   // coalesced
#pragma unroll
                    for (int j = 0; j < 4; ++j) a2[j] = fmaf(h32[rq + j][h], w, a2[j]);
                }
#pragma unroll
                for (int j = 0; j < 4; ++j) z32[rq + j][ii] += a2[j];
            }
            __syncthreads();
            W1T = W1Tb; W2T = W2Tb;
        }
        {   // dist: t = (r 0..31, c 0..31 -> 4 d's); part overlays h32
            float* part = &h32[0][0];
            const int r = t >> 5, c = t & 31;
            const int bl = rowb[rb0 + (r < nr ? r : 0)];
            float s = 0.f;
#pragma unroll
            for (int i = 0; i < 4; ++i) {
                int d = c * 4 + i;
                float v = z32[r][d] + xhat[(b0 + bl) * 128 + d] - x[(b0 + bl) * 128 + d];
                s = fmaf(v, v, s);
            }
            part[r * 32 + c] = s;
        }
        if (t < 8) copyrow[t] = -1;
        __syncthreads();
        if (t < 32) {
            float* part = &h32[0][0];
            float ssum = 0.f;
#pragma unroll
            for (int c2 = 0; c2 < 32; ++c2) ssum += part[t * 32 + c2];
            dd[t] = ssum;
        }
        __syncthreads();
        if (t < 8) {   // rows k-ascending; strict < keeps lowest k
            for (int r = 0; r < nr; ++r) {
                if (rowb[rb0 + r] == t && dd[r] < dbest[t]) {
                    dbest[t] = dd[r];
                    kbest[t] = rowk[rb0 + r];
                    copyrow[t] = r;
                }
            }
        }
        __syncthreads();
        if (t < 128) {
#pragma unroll 1
            for (int bl = 0; bl < 8; ++bl) {
                int cr = copyrow[bl];
                if (cr >= 0) zwin[bl][t] = z32[cr][t];
            }
        }
        __syncthreads();
    }

    if (t < 8) out0[b0 + t] = (float)kbest[t];
    {   // outd: 1024 elems, one per thread
        int bl = t >> 7, d = t & 127;
        outd[(b0 + bl) * 128 + d] = zwin[bl][d];
    }
}

extern "C" void kernel_launch(void* const* d_in, const int* in_sizes, int n_in,
                              void* d_out, int out_size, void* d_ws, size_t ws_size,
                              hipStream_t stream) {
    const float* xhat = (const float*)d_in[0];
    const float* x    = (const float*)d_in[1];
    const float* cb   = (const float*)d_in[2];
    const float* Wc   = (const float*)d_in[3];
    const float* bc   = (const float*)d_in[4];
    const float* W1_0 = (const float*)d_in[5];
    const float* W2_0 = (const float*)d_in[6];
    const float* W1_1 = (const float*)d_in[7];
    const float* W2_1 = (const float*)d_in[8];
    float* out = (float*)d_out;
    float* ws  = (float*)d_ws;

    float* WzT   = ws + 0;
    float* WxT   = ws + 16384;
    float* W1T0  = ws + 32768;
    float* W2T0  = ws + 65536;
    float* W1T1  = ws + 98304;
    float* W2T1  = ws + 131072;
    float* z0    = ws + 163840;
    float* u     = ws + 196608;
    unsigned short* z0bf = (unsigned short*)(ws + 458752);
    unsigned short* ubf  = (unsigned short*)(ws + 475136);
    unsigned short* U1bf = (unsigned short*)(ws + 606208);
    unsigned short* H1bf = (unsigned short*)(ws + 868352);
    uint4* F     = (uint4*)(ws + 901120);
    const uint4* W2f0 = F;
    const uint4* W1f1 = F + 4096;
    const uint4* W2f1 = F + 8192;
    int* cand = (int*)(ws + 950272);
    int* cnt  = (int*)(ws + 983040);

    k_prep1<<<688, 256, 0, stream>>>(Wc, W1_0, W2_0, W1_1, W2_1,
                                     WzT, WxT, W1T0, W2T0, W1T1, W2T1, F);
    k_prep2<<<576, 256, 0, stream>>>(cb, bc, xhat, WzT, WxT, W1T0,
                                     z0, z0bf, H1bf, u, ubf, U1bf);
    k_dist_approx<<<4096, 512, 0, stream>>>(z0bf, ubf, xhat, x, (const uint4*)H1bf,
                                            U1bf, W2f0, W1f1, W2f1, cand, cnt);
    k_final4<<<256, 1024, 0, stream>>>(z0, u, xhat, x, cand, cnt,
                                       W1T0, W2T0, W1T1, W2T1, out, out + 2048);
}

// Round 12
// 319.557 us; speedup vs baseline: 1.4296x; 1.0383x over previous
//
#include <hip/hip_runtime.h>

// QINCoStep — bs=2048, d=128, K=256, h=256, fp32 in/out.
// Round 12: R11 with k_final5 — exact pass rewritten with float4 LDS
// broadcasts + register tiling (R11's k_final4 was LDS-scalar-read bound:
// ~128 us vs 14 us VALU floor).
//
// ws layout (floats):
//   0 WzT 16384 | 16384 WxT 16384 | 32768 W1T0 32768 | 65536 W2T0 32768
//   98304 W1T1 32768 | 131072 W2T1 32768 | 163840 z0 32768 | 196608 u 262144
//   458752 z0bf | 475136 ubf | 606208 U1bf | 868352 H1bf
//   901120 F (12288 uint4) | 950272 cand (32768 int) | 983040 cnt (4096 int)

typedef short bf8_t __attribute__((ext_vector_type(8)));
typedef float f32x16 __attribute__((ext_vector_type(16)));

__device__ inline unsigned short f2bh(float x) {   // RNE f32->bf16 (prep only)
    unsigned u = __float_as_uint(x);
    u += 0x7fffu + ((u >> 16) & 1u);
    return (unsigned short)(u >> 16);
}
__device__ inline float bh2f(unsigned short h) {
    return __uint_as_float(((unsigned)h) << 16);
}
__device__ inline f32x16 mfma_bf(uint4 a, uint4 b, f32x16 c) {
    bf8_t av = __builtin_bit_cast(bf8_t, a);
    bf8_t bv = __builtin_bit_cast(bf8_t, b);
    return __builtin_amdgcn_mfma_f32_32x32x16_bf16(av, bv, c, 0, 0, 0);
}
__device__ inline unsigned packhi(float x, float y) {
    return __builtin_amdgcn_perm(__float_as_uint(y), __float_as_uint(x), 0x07060302u);
}
__device__ inline unsigned addrelu2t(unsigned hv, unsigned uv) {
    float a0 = __uint_as_float(hv << 16) + __uint_as_float(uv << 16);
    float a1 = __uint_as_float(hv & 0xFFFF0000u) + __uint_as_float(uv & 0xFFFF0000u);
    return packhi(fmaxf(a0, 0.f), fmaxf(a1, 0.f));
}

#define DELTA 6.5f

// ---------------- prep1: transposes + frag pack (unchanged) ----------------
__global__ __launch_bounds__(256) void k_prep1(
    const float* __restrict__ Wc,
    const float* __restrict__ W1a, const float* __restrict__ W2a,
    const float* __restrict__ W1b, const float* __restrict__ W2b,
    float* __restrict__ WzT, float* __restrict__ WxT,
    float* __restrict__ W1Ta, float* __restrict__ W2Ta,
    float* __restrict__ W1Tb, float* __restrict__ W2Tb,
    uint4* __restrict__ F)
{
    int g = blockIdx.x * 256 + threadIdx.x;
    if (g < 16384) {
        int j = g >> 7, d = g & 127;
        WzT[g] = Wc[d * 256 + j];
    } else if (g < 32768) {
        int e = g - 16384; int j = e >> 7, d = e & 127;
        WxT[e] = Wc[d * 256 + 128 + j];
    } else if (g < 65536) {
        int e = g - 32768; int d = e >> 8, h = e & 255;
        W1Ta[e] = W1a[h * 128 + d];
    } else if (g < 98304) {
        int e = g - 65536; int h = e >> 7, i = e & 127;
        W2Ta[e] = W2a[i * 256 + h];
    } else if (g < 131072) {
        int e = g - 98304; int d = e >> 8, h = e & 255;
        W1Tb[e] = W1b[h * 128 + d];
    } else if (g < 163840) {
        int e = g - 131072; int h = e >> 7, i = e & 127;
        W2Tb[e] = W2b[i * 256 + h];
    } else if (g < 176128) {   // 12288 frag-lane slots (RNE)
        int idx = g - 163840;
        int mat = idx >> 12, fp = idx & 4095;
        int tile = fp >> 6, lane = fp & 63;
        const float* src;
        if (mat == 1) {            // W1_1: [256][128], 8mt x 8kt
            int mt = tile >> 3, kt = tile & 7;
            src = W1b + (32 * mt + (lane & 31)) * 128 + 16 * kt + 8 * (lane >> 5);
        } else {                   // W2-type: [128][256], 4mt x 16kt
            const float* W = (mat == 0) ? W2a : W2b;
            int mt = tile >> 4, kt = tile & 15;
            src = W + (32 * mt + (lane & 31)) * 256 + 16 * kt + 8 * (lane >> 5);
        }
        unsigned short hs[8];
#pragma unroll
        for (int j = 0; j < 8; ++j) hs[j] = f2bh(src[j]);
        uint4 hv;
        hv.x = (unsigned)hs[0] | ((unsigned)hs[1] << 16);
        hv.y = (unsigned)hs[2] | ((unsigned)hs[3] << 16);
        hv.z = (unsigned)hs[4] | ((unsigned)hs[5] << 16);
        hv.w = (unsigned)hs[6] | ((unsigned)hs[7] << 16);
        F[idx] = hv;
    }
}

// ---------------- prep2 (unchanged) ----------------
__global__ __launch_bounds__(256) void k_prep2(
    const float* __restrict__ cb, const float* __restrict__ bc,
    const float* __restrict__ xhat,
    const float* __restrict__ WzT, const float* __restrict__ WxT,
    const float* __restrict__ W1T0,
    float* __restrict__ z0, unsigned short* __restrict__ z0bf,
    unsigned short* __restrict__ H1bf,
    float* __restrict__ u, unsigned short* __restrict__ ubf,
    unsigned short* __restrict__ U1bf)
{
    __shared__ float src[4][128];
    __shared__ float res[4][128];
    const int t = threadIdx.x;
    const bool krole = blockIdx.x < 64;
    const int r0 = (krole ? blockIdx.x : (blockIdx.x - 64)) * 4;
    const float* in = krole ? cb : xhat;
    const float* WT = krole ? WzT : WxT;
#pragma unroll
    for (int e = t; e < 512; e += 256)
        src[e >> 7][e & 127] = in[(r0 + (e >> 7)) * 128 + (e & 127)];
    __syncthreads();
    {
        const int d = t & 127, r = t >> 7;   // rows r, r+2
        float a0 = krole ? (bc[d] + src[r][d]) : 0.f;
        float a1 = krole ? (bc[d] + src[r + 2][d]) : 0.f;
        for (int j = 0; j < 128; ++j) {
            const float w = WT[j * 128 + d];
            a0 = fmaf(src[r][j], w, a0);
            a1 = fmaf(src[r + 2][j], w, a1);
        }
        float* dst = krole ? z0 : u;
        unsigned short* dstbf = krole ? z0bf : ubf;
        dst[(r0 + r) * 128 + d] = a0;        dstbf[(r0 + r) * 128 + d] = f2bh(a0);
        dst[(r0 + r + 2) * 128 + d] = a1;    dstbf[(r0 + r + 2) * 128 + d] = f2bh(a1);
        res[r][d] = a0; res[r + 2][d] = a1;
    }
    __syncthreads();
    {
        float a[4] = {0.f, 0.f, 0.f, 0.f};
        for (int d = 0; d < 128; ++d) {
            const float w = W1T0[d * 256 + t];
#pragma unroll
            for (int r = 0; r < 4; ++r) a[r] = fmaf(res[r][d], w, a[r]);
        }
        if (krole) {
            const int kt = t >> 4, half = (t >> 3) & 1, j = t & 7;
#pragma unroll
            for (int r = 0; r < 4; ++r) {
                int k = r0 + r; int kg = k >> 5, col = k & 31;
                H1bf[(((kg * 16 + kt) * 64) + half * 32 + col) * 8 + j] = f2bh(a[r]);
            }
        } else {
#pragma unroll
            for (int r = 0; r < 4; ++r)
                U1bf[(r0 + r) * 256 + t] = f2bh(a[r]);
        }
    }
}

// ---------------- main: approx dist + fused per-half select (unchanged) ----------------
__global__ __launch_bounds__(512, 6) void k_dist_approx(
    const unsigned short* __restrict__ z0bf, const unsigned short* __restrict__ ubf,
    const float* __restrict__ xhat, const float* __restrict__ x,
    const uint4* __restrict__ H1u4, const unsigned short* __restrict__ U1bf,
    const uint4* __restrict__ W2f0, const uint4* __restrict__ W1f1,
    const uint4* __restrict__ W2f1,
    int* __restrict__ cand, int* __restrict__ cnt)
{
    __shared__ uint4 Zf[2048];   // 32 KB
    __shared__ uint4 Hf[1024];   // 16 KB; tail reused for red/sdist/sk

    const int t = threadIdx.x;
    const int lane = t & 63, wave = t >> 6;
    const int wm = wave & 3, wn = wave >> 2;
    const int l31 = lane & 31, l5 = lane >> 5;
    const int b = blockIdx.x >> 1, q = blockIdx.x & 1;
    const int k0 = q << 7;

    f32x16 zs[2];
    {
        const unsigned short* ur = ubf + b * 128;
#pragma unroll
        for (int g = 0; g < 2; ++g) {
            const int col = ((wn << 1) + g) * 32 + l31;
            const unsigned short* zr = z0bf + (k0 + col) * 128;
#pragma unroll
            for (int rg = 0; rg < 4; ++rg) {
                const int d0 = 32 * wm + 8 * rg + 4 * l5;
                ushort4 a = *(const ushort4*)(zr + d0);
                ushort4 c = *(const ushort4*)(ur + d0);
                zs[g][4*rg+0] = bh2f(a.x) + bh2f(c.x);
                zs[g][4*rg+1] = bh2f(a.y) + bh2f(c.y);
                zs[g][4*rg+2] = bh2f(a.z) + bh2f(c.z);
                zs[g][4*rg+3] = bh2f(a.w) + bh2f(c.w);
            }
        }
    }

#pragma unroll 1
    for (int r = 0; r < 4; ++r) {
        {
            const int kt = 4 * r + wm;
            const uint4 uv = *(const uint4*)(U1bf + b * 256 + kt * 16 + 8 * l5);
#pragma unroll
            for (int gi = 0; gi < 2; ++gi) {
                const int cg = (wn << 1) + gi;
                const int kg = (q << 2) + cg;
                uint4 hv = H1u4[(kg * 16 + kt) * 64 + lane];
                uint4 o;
                o.x = addrelu2t(hv.x, uv.x);
                o.y = addrelu2t(hv.y, uv.y);
                o.z = addrelu2t(hv.z, uv.z);
                o.w = addrelu2t(hv.w, uv.w);
                Hf[((cg << 2) + wm) * 64 + lane] = o;
            }
        }
        __syncthreads();
#pragma unroll
        for (int ktl = 0; ktl < 4; ++ktl) {
            uint4 ah = W2f0[((wm << 4) + 4 * r + ktl) * 64 + lane];
#pragma unroll
            for (int g = 0; g < 2; ++g) {
                uint4 bv = Hf[((((wn << 1) + g) << 2) + ktl) * 64 + lane];
                zs[g] = mfma_bf(ah, bv, zs[g]);
            }
        }
        __syncthreads();
    }

#pragma unroll
    for (int g = 0; g < 2; ++g) {
        const int cg = (wn << 1) + g;
#pragma unroll
        for (int rg = 0; rg < 4; ++rg) {
            uint2 hv;
            hv.x = packhi(zs[g][4*rg+0], zs[g][4*rg+1]);
            hv.y = packhi(zs[g][4*rg+2], zs[g][4*rg+3]);
            uint2* zb2 = (uint2*)&Zf[((cg << 3) + 2 * wm + (rg >> 1)) * 64];
            zb2[(((rg & 1) << 5) + l31) * 2 + l5] = hv;
        }
    }
    __syncthreads();

    const int tile = wave & 1, cg1 = wave >> 1;
#pragma unroll 1
    for (int c = 0; c < 4; ++c) {
        f32x16 acc;
#pragma unroll
        for (int rr = 0; rr < 16; ++rr) acc[rr] = 0.f;
        {
            const uint4* pw1 = W1f1 + ((2 * c + tile) << 3) * 64;
#pragma unroll
            for (int kt = 0; kt < 8; ++kt) {
                uint4 bv = Zf[((cg1 << 3) + kt) * 64 + lane];
                uint4 ah = pw1[kt * 64 + lane];
                acc = mfma_bf(ah, bv, acc);
            }
        }
        __syncthreads();
#pragma unroll
        for (int rg = 0; rg < 4; ++rg) {
            float v0 = fmaxf(acc[4*rg+0], 0.f), v1 = fmaxf(acc[4*rg+1], 0.f);
            float v2 = fmaxf(acc[4*rg+2], 0.f), v3 = fmaxf(acc[4*rg+3], 0.f);
            uint2 hv; hv.x = packhi(v0, v1); hv.y = packhi(v2, v3);
            uint2* hb2 = (uint2*)&Hf[((cg1 << 2) + (tile << 1) + (rg >> 1)) * 64];
            hb2[(((rg & 1) << 5) + l31) * 2 + l5] = hv;
        }
        __syncthreads();
#pragma unroll
        for (int ktl = 0; ktl < 4; ++ktl) {
            uint4 ah = W2f1[((wm << 4) + 4 * c + ktl) * 64 + lane];
#pragma unroll
            for (int g = 0; g < 2; ++g) {
                uint4 bv = Hf[((((wn << 1) + g) << 2) + ktl) * 64 + lane];
                zs[g] = mfma_bf(ah, bv, zs[g]);
            }
        }
    }

    float* red   = (float*)Hf;          // [4][128]
    float* sdist = (float*)Hf + 512;    // [128]
    int*   sk    = (int*)((float*)Hf + 640);   // [8]
    __syncthreads();
#pragma unroll
    for (int g = 0; g < 2; ++g) {
        float s = 0.f;
        const int col = ((wn << 1) + g) * 32 + l31;
#pragma unroll
        for (int rg = 0; rg < 4; ++rg) {
            const int d0 = 32 * wm + 8 * rg + 4 * l5;
            float4 xh = *(const float4*)(xhat + b * 128 + d0);
            float4 xx = *(const float4*)(x + b * 128 + d0);
            float v;
            v = zs[g][4*rg+0] + xh.x - xx.x; s = fmaf(v, v, s);
            v = zs[g][4*rg+1] + xh.y - xx.y; s = fmaf(v, v, s);
            v = zs[g][4*rg+2] + xh.z - xx.z; s = fmaf(v, v, s);
            v = zs[g][4*rg+3] + xh.w - xx.w; s = fmaf(v, v, s);
        }
        s += __shfl_xor(s, 32, 64);
        if (l5 == 0) red[wm * 128 + col] = s;
    }
    __syncthreads();
    if (t < 128)
        sdist[t] = red[t] + red[128 + t] + red[256 + t] + red[384 + t];
    __syncthreads();
    if (wave == 0) {
        int base = 0;
        float v0 = sdist[lane], v1 = sdist[lane + 64];
        float m = fminf(v0, v1);
#pragma unroll
        for (int off = 32; off > 0; off >>= 1) m = fminf(m, __shfl_xor(m, off, 64));
        const float thr = m + DELTA;
        const unsigned long long below = (1ull << lane) - 1;
        float vv[2] = {v0, v1};
#pragma unroll
        for (int j = 0; j < 2; ++j) {
            bool p = vv[j] <= thr;
            unsigned long long mask = __ballot(p);
            int pos = base + __popcll(mask & below);
            if (p && pos < 8) sk[pos] = k0 + 64 * j + lane;   // k-ascending order
            base += __popcll(mask);
        }
        if (lane == 0) {
            int c = base > 8 ? 8 : base;
            cnt[b * 2 + q] = c;
            for (int s2 = 0; s2 < c; ++s2)
                cand[(b * 2 + q) * 8 + s2] = sk[s2];
        }
    }
}

// ---------------- final5: 4 b's / wg, 256 thr, float4-LDS register-tiled exact pass ----------------
__global__ __launch_bounds__(256) void k_final5(
    const float* __restrict__ z0, const float* __restrict__ u,
    const float* __restrict__ xhat, const float* __restrict__ x,
    const int* __restrict__ cand, const int* __restrict__ cnt,
    const float* __restrict__ W1Ta, const float* __restrict__ W2Ta,
    const float* __restrict__ W1Tb, const float* __restrict__ W2Tb,
    float* __restrict__ out0, float* __restrict__ outd)
{
    __shared__ float z16[16][128];    // 8 KB
    __shared__ float h16[16][256];    // 16 KB (overlaid as part[16][16] for dist)
    __shared__ float zwin[4][128];    // 2 KB
    __shared__ int rowb[64], rowk[64];
    __shared__ int off4[4];
    __shared__ int rtot;
    __shared__ float dd[16];
    __shared__ float dbest[4];
    __shared__ int kbest[4];
    __shared__ int copyrow[4];
    const int t = threadIdx.x;
    const int b0 = blockIdx.x * 4;

    if (t < 4) {
        off4[t] = cnt[2 * (b0 + t)] + cnt[2 * (b0 + t) + 1];
        dbest[t] = 3.4e38f;
        kbest[t] = 0;
    }
    __syncthreads();
    if (t == 0) {
        int a = 0;
        for (int i = 0; i < 4; ++i) { int v = off4[i]; off4[i] = a; a += v; }
        rtot = a;
    }
    __syncthreads();
    if (t < 4) {   // rows k-ascending per b (half0 ks < half1 ks)
        int c0 = cnt[2 * (b0 + t)], c1 = cnt[2 * (b0 + t) + 1];
        int o = off4[t];
        for (int s = 0; s < c0; ++s) { rowb[o] = t; rowk[o] = cand[(2 * (b0 + t)) * 8 + s]; ++o; }
        for (int s = 0; s < c1; ++s) { rowb[o] = t; rowk[o] = cand[(2 * (b0 + t) + 1) * 8 + s]; ++o; }
    }
    __syncthreads();
    const int R = rtot;
    const int nb = (R + 15) >> 4;

#pragma unroll 1
    for (int batch = 0; batch < nb; ++batch) {
        const int rb0 = batch * 16;
        const int nr = (R - rb0) < 16 ? (R - rb0) : 16;
#pragma unroll
        for (int n = 0; n < 8; ++n) {   // z init: 2048 elems / 256 thr
            int e = n * 256 + t; int r = e >> 7, d = e & 127;
            int rg = rb0 + (r < nr ? r : 0);
            z16[r][d] = z0[rowk[rg] * 128 + d] + u[(b0 + rowb[rg]) * 128 + d];
        }
        __syncthreads();
        const float* W1T = W1Ta; const float* W2T = W2Ta;
#pragma unroll 1
        for (int blk = 0; blk < 2; ++blk) {
            {   // G1: thread = (hq = t&63 -> 4 h's, rq = t>>6 -> 4 rows)
                const int hq = t & 63, rq = t >> 6;
                float acc[4][4];
#pragma unroll
                for (int r = 0; r < 4; ++r) {
                    acc[r][0] = 0.f; acc[r][1] = 0.f; acc[r][2] = 0.f; acc[r][3] = 0.f;
                }
#pragma unroll 2
                for (int d = 0; d < 128; d += 4) {
                    const float* wb = W1T + d * 256 + 4 * hq;
                    float4 w0 = *(const float4*)(wb);
                    float4 w1 = *(const float4*)(wb + 256);
                    float4 w2 = *(const float4*)(wb + 512);
                    float4 w3 = *(const float4*)(wb + 768);
#pragma unroll
                    for (int r = 0; r < 4; ++r) {
                        float4 zv = *(const float4*)&z16[4 * rq + r][d];   // b128 broadcast
                        acc[r][0] = fmaf(zv.x, w0.x, fmaf(zv.y, w1.x, fmaf(zv.z, w2.x, fmaf(zv.w, w3.x, acc[r][0]))));
                        acc[r][1] = fmaf(zv.x, w0.y, fmaf(zv.y, w1.y, fmaf(zv.z, w2.y, fmaf(zv.w, w3.y, acc[r][1]))));
                        acc[r][2] = fmaf(zv.x, w0.z, fmaf(zv.y, w1.z, fmaf(zv.z, w2.z, fmaf(zv.w, w3.z, acc[r][2]))));
                        acc[r][3] = fmaf(zv.x, w0.w, fmaf(zv.y, w1.w, fmaf(zv.z, w2.w, fmaf(zv.w, w3.w, acc[r][3]))));
                    }
                }
#pragma unroll
                for (int r = 0; r < 4; ++r) {
                    float4 o;
                    o.x = fmaxf(acc[r][0], 0.f); o.y = fmaxf(acc[r][1], 0.f);
                    o.z = fmaxf(acc[r][2], 0.f); o.w = fmaxf(acc[r][3], 0.f);
                    *(float4*)&h16[4 * rq + r][4 * hq] = o;                // b128 write
                }
            }
            __syncthreads();
            {   // G2: thread = (iq = t&31 -> 4 i's, rq2 = t>>5 -> 2 rows)
                const int iq = t & 31, rq2 = t >> 5;   // rq2 0..7
                float a2[2][4];
                a2[0][0] = 0.f; a2[0][1] = 0.f; a2[0][2] = 0.f; a2[0][3] = 0.f;
                a2[1][0] = 0.f; a2[1][1] = 0.f; a2[1][2] = 0.f; a2[1][3] = 0.f;
#pragma unroll 2
                for (int h = 0; h < 256; h += 4) {
                    const float* wb = W2T + h * 128 + 4 * iq;
                    float4 w0 = *(const float4*)(wb);
                    float4 w1 = *(const float4*)(wb + 128);
                    float4 w2 = *(const float4*)(wb + 256);
                    float4 w3 = *(const float4*)(wb + 384);
#pragma unroll
                    for (int r = 0; r < 2; ++r) {
                        float4 hv = *(const float4*)&h16[2 * rq2 + r][h];  // b128, 2-way split (free)
                        a2[r][0] = fmaf(hv.x, w0.x, fmaf(hv.y, w1.x, fmaf(hv.z, w2.x, fmaf(hv.w, w3.x, a2[r][0]))));
                        a2[r][1] = fmaf(hv.x, w0.y, fmaf(hv.y, w1.y, fmaf(hv.z, w2.y, fmaf(hv.w, w3.y, a2[r][1]))));
                        a2[r][2] = fmaf(hv.x, w0.z, fmaf(hv.y, w1.z, fmaf(hv.z, w2.z, fmaf(hv.w, w3.z, a2[r][2]))));
                        a2[r][3] = fmaf(hv.x, w0.w, fmaf(hv.y, w1.w, fmaf(hv.z, w2.w, fmaf(hv.w, w3.w, a2[r][3]))));
                    }
                }
#pragma unroll
                for (int r = 0; r < 2; ++r) {
                    float4 zo = *(const float4*)&z16[2 * rq2 + r][4 * iq];
                    zo.x += a2[r][0]; zo.y += a2[r][1]; zo.z += a2[r][2]; zo.w += a2[r][3];
                    *(float4*)&z16[2 * rq2 + r][4 * iq] = zo;
                }
            }
            __syncthreads();
            W1T = W1Tb; W2T = W2Tb;
        }
        // dist (part overlays h16; h16 readers done at last sync)
        {
            float* part = &h16[0][0];
            const int r = t >> 4, c = t & 15;
            const int bl = rowb[rb0 + (r < nr ? r : 0)];
            const float* xh = xhat + (b0 + bl) * 128;
            const float* xx = x + (b0 + bl) * 128;
            float s = 0.f;
#pragma unroll
            for (int i = 0; i < 8; ++i) {
                int d = c * 8 + i;
                float v = z16[r][d] + xh[d] - xx[d];
                s = fmaf(v, v, s);
            }
            part[r * 16 + c] = s;
        }
        if (t < 4) copyrow[t] = -1;
        __syncthreads();
        if (t < 16) {
            float* part = &h16[0][0];
            float ss = 0.f;
#pragma unroll
            for (int c2 = 0; c2 < 16; ++c2) ss += part[t * 16 + c2];
            dd[t] = ss;
        }
        __syncthreads();
        if (t < 4) {   // rows k-ascending; strict < keeps lowest k
            for (int r = 0; r < nr; ++r) {
                if (rowb[rb0 + r] == t && dd[r] < dbest[t]) {
                    dbest[t] = dd[r];
                    kbest[t] = rowk[rb0 + r];
                    copyrow[t] = r;
                }
            }
        }
        __syncthreads();
        if (t < 128) {
#pragma unroll 1
            for (int bl = 0; bl < 4; ++bl) {
                int cr = copyrow[bl];
                if (cr >= 0) zwin[bl][t] = z16[cr][t];
            }
        }
        __syncthreads();
    }

    if (t < 4) out0[b0 + t] = (float)kbest[t];
#pragma unroll
    for (int n = 0; n < 2; ++n) {
        int e = n * 256 + t; int bl = e >> 7, d = e & 127;
        outd[(b0 + bl) * 128 + d] = zwin[bl][d];
    }
}

extern "C" void kernel_launch(void* const* d_in, const int* in_sizes, int n_in,
                              void* d_out, int out_size, void* d_ws, size_t ws_size,
                              hipStream_t stream) {
    const float* xhat = (const float*)d_in[0];
    const float* x    = (const float*)d_in[1];
    const float* cb   = (const float*)d_in[2];
    const float* Wc   = (const float*)d_in[3];
    const float* bc   = (const float*)d_in[4];
    const float* W1_0 = (const float*)d_in[5];
    const float* W2_0 = (const float*)d_in[6];
    const float* W1_1 = (const float*)d_in[7];
    const float* W2_1 = (const float*)d_in[8];
    float* out = (float*)d_out;
    float* ws  = (float*)d_ws;

    float* WzT   = ws + 0;
    float* WxT   = ws + 16384;
    float* W1T0  = ws + 32768;
    float* W2T0  = ws + 65536;
    float* W1T1  = ws + 98304;
    float* W2T1  = ws + 131072;
    float* z0    = ws + 163840;
    float* u     = ws + 196608;
    unsigned short* z0bf = (unsigned short*)(ws + 458752);
    unsigned short* ubf  = (unsigned short*)(ws + 475136);
    unsigned short* U1bf = (unsigned short*)(ws + 606208);
    unsigned short* H1bf = (unsigned short*)(ws + 868352);
    uint4* F     = (uint4*)(ws + 901120);
    const uint4* W2f0 = F;
    const uint4* W1f1 = F + 4096;
    const uint4* W2f1 = F + 8192;
    int* cand = (int*)(ws + 950272);
    int* cnt  = (int*)(ws + 983040);

    k_prep1<<<688, 256, 0, stream>>>(Wc, W1_0, W2_0, W1_1, W2_1,
                                     WzT, WxT, W1T0, W2T0, W1T1, W2T1, F);
    k_prep2<<<576, 256, 0, stream>>>(cb, bc, xhat, WzT, WxT, W1T0,
                                     z0, z0bf, H1bf, u, ubf, U1bf);
    k_dist_approx<<<4096, 512, 0, stream>>>(z0bf, ubf, xhat, x, (const uint4*)H1bf,
                                            U1bf, W2f0, W1f1, W2f1, cand, cnt);
    k_final5<<<512, 256, 0, stream>>>(z0, u, xhat, x, cand, cnt,
                                      W1T0, W2T0, W1T1, W2T1, out, out + 2048);
}